// Round 13
// baseline (369.330 us; speedup 1.0000x reference)
//
#include <hip/hip_runtime.h>
#include <stdint.h>

#define BS_T   16384
#define XDIM   4096
#define KDIM   512
#define NKEYS  4096
#define KTOP   16

typedef _Float16 half8  __attribute__((ext_vector_type(8)));
typedef float    floatx4 __attribute__((ext_vector_type(4)));

// async global->LDS, 16B per lane; LDS dest is wave-uniform base + lane*16
__device__ static inline void gload_lds16(const void* g, void* l) {
  __builtin_amdgcn_global_load_lds(
      (const __attribute__((address_space(1))) uint32_t*)(uintptr_t)g,
      (__attribute__((address_space(3))) uint32_t*)(uint32_t)(uintptr_t)l,
      16, 0, 0);
}

#define SBAR() __builtin_amdgcn_sched_barrier(0)
#define LGKM0() asm volatile("s_waitcnt lgkmcnt(0)" ::: "memory")
#define FULL_BAR() do { __builtin_amdgcn_sched_barrier(0); \
                        __builtin_amdgcn_s_barrier(); \
                        __builtin_amdgcn_sched_barrier(0); } while (0)

// ---------------- fp32 -> fp16 convert (vectorized, grid-stride) ----------------
__global__ __launch_bounds__(256) void cvt_f32_f16_v(const float* __restrict__ in,
                                                     _Float16* __restrict__ out, int n8) {
  int stride = gridDim.x * 256;
  for (int i = blockIdx.x * 256 + threadIdx.x; i < n8; i += stride) {
    float4 v0 = ((const float4*)in)[2 * i];
    float4 v1 = ((const float4*)in)[2 * i + 1];
    half8 h = { (_Float16)v0.x, (_Float16)v0.y, (_Float16)v0.z, (_Float16)v0.w,
                (_Float16)v1.x, (_Float16)v1.y, (_Float16)v1.z, (_Float16)v1.w };
    ((half8*)out)[i] = h;
  }
}

// ---------------- GEMM1 v8: Q[M,512] = cvt16(X[M,4096]) @ W16^T + b ---------------
// x read ONCE with 1KB-contiguous per-row chunks (DRAM row-buffer friendly):
// A staged in K-chunks of 256 (dbuf 2x32KB), loads spread 2xfloat4/thread/step.
// B (W16, L2-resident) is WAVE-PRIVATE depth-1 single-buffer (64KB): stage(t+1)
// after own reads retire (lgkm0), gate vmcnt(2) same step — no barriers for B.
// ONE barrier per chunk (post-write). LDS total 128 KB. 8 waves, 32 MFMA/step.
__global__ __launch_bounds__(512, 1)
void gemm1_pipe(const float* __restrict__ X, const _Float16* __restrict__ Wh,
                const float* __restrict__ bias, _Float16* __restrict__ Q) {
  __shared__ __align__(16) _Float16 ldsA[2][64 * 256];   // 2 x 32 KB (chunk = K256)
  __shared__ __align__(16) _Float16 ldsB[512 * 64];      // 64 KB, wave-private

  const int tid  = threadIdx.x;
  const int lane = tid & 63;
  const int wid  = tid >> 6;            // 0..7
  const int rowBase = blockIdx.x * 64;
  const int wc  = wid * 64;
  const int l15 = lane & 15;
  const int q4  = lane >> 4;
  const int sub   = lane >> 3;
  const int gslot = (lane & 7) ^ sub;

  // A chunk staging: thread -> row tid>>3, col-span s*32..s*32+31 (contiguous 128B)
  const int arow = tid >> 3;
  const int s    = tid & 7;
  const float* aSrc = X + (size_t)(rowBase + arow) * XDIM + s * 32;
  const int au    = (s >> 1) * 8192;    // sub-tile (64-col) offset
  const int abyte = arow * 128;
  const int aswz  = (arow & 7) << 4;

  const _Float16* const bSrc = Wh + (size_t)(wc + sub) * XDIM + gslot * 8;
  char* const bDst = (char*)ldsB + wid * 8192;

  auto stageB = [&](int kt) {
    #pragma unroll
    for (int i = 0; i < 8; ++i)
      gload_lds16(bSrc + (size_t)i * 8 * XDIM + kt, bDst + i * 1024);
  };
  auto wrA = [&](char* base, int k, float4 v0, float4 v1) {
    half8 h = { (_Float16)v0.x, (_Float16)v0.y, (_Float16)v0.z, (_Float16)v0.w,
                (_Float16)v1.x, (_Float16)v1.y, (_Float16)v1.z, (_Float16)v1.w };
    const int w = (s & 1) * 4 + k;
    *(half8*)(base + au + abyte + ((w * 16) ^ aswz)) = h;
  };
  auto ld8 = [&](const char* base, int row, int w) {
    return *(const half8*)(base + row * 128 + ((w * 16) ^ ((row & 7) << 4)));
  };

  floatx4 acc[4][4];
  #pragma unroll
  for (int m = 0; m < 4; ++m)
    #pragma unroll
    for (int n = 0; n < 4; ++n)
      acc[m][n] = (floatx4)0.0f;

  half8 a[4][2], b[4][2];
  auto readFrags = [&](const char* aB) {
    #pragma unroll
    for (int m = 0; m < 4; ++m)
      #pragma unroll
      for (int kk = 0; kk < 2; ++kk)
        a[m][kk] = ld8(aB, m * 16 + l15, kk * 4 + q4);
    #pragma unroll
    for (int n = 0; n < 4; ++n)
      #pragma unroll
      for (int kk = 0; kk < 2; ++kk)
        b[n][kk] = ld8((const char*)ldsB, wc + n * 16 + l15, kk * 4 + q4);
  };
  auto mfma32 = [&]() {
    __builtin_amdgcn_s_setprio(1);
    #pragma unroll
    for (int m = 0; m < 4; ++m)
      #pragma unroll
      for (int n = 0; n < 4; ++n)
        #pragma unroll
        for (int kk = 0; kk < 2; ++kk)
          acc[m][n] = __builtin_amdgcn_mfma_f32_16x16x32_f16(a[m][kk], b[n][kk], acc[m][n], 0, 0, 0);
    __builtin_amdgcn_s_setprio(0);
  };

  float4 P0a, P0b, P1a, P1b, P2a, P2b, P3a, P3b, N0a, N0b;

  // ---- prologue: chunk0 -> ldsA[0]; B tile0 staged; chunk1 pair0 in flight ----
  {
    float4 C0 = *(const float4*)(aSrc + 0),  C1 = *(const float4*)(aSrc + 4);
    float4 C2 = *(const float4*)(aSrc + 8),  C3 = *(const float4*)(aSrc + 12);
    float4 C4 = *(const float4*)(aSrc + 16), C5 = *(const float4*)(aSrc + 20);
    float4 C6 = *(const float4*)(aSrc + 24), C7 = *(const float4*)(aSrc + 28);
    SBAR();
    stageB(0);
    SBAR();
    P0a = *(const float4*)(aSrc + 256);
    P0b = *(const float4*)(aSrc + 260);
    SBAR();
    char* w0 = (char*)&ldsA[0][0];
    wrA(w0, 0, C0, C1); wrA(w0, 1, C2, C3);
    wrA(w0, 2, C4, C5); wrA(w0, 3, C6, C7);   // implicit vmcnt waits chunk0 loads
    LGKM0();
    asm volatile("s_waitcnt vmcnt(2)" ::: "memory");   // retire B(0); P0 flies
    FULL_BAR();
  }

  for (int c = 0; c < 16; ++c) {
    const char* aB = (const char*)&ldsA[c & 1][0];
    const int t0 = c * 4;
    const int cb = (c + 1) * 256;

    // ---------- q0 (tile t0, sub-tile 0) ----------
    readFrags(aB);
    LGKM0(); SBAR();
    stageB((t0 + 1) * 64);
    SBAR();
    if (c < 15) { P1a = *(const float4*)(aSrc + cb + 8);
                  P1b = *(const float4*)(aSrc + cb + 12); }
    SBAR();
    mfma32();
    SBAR();
    if (c < 15) asm volatile("s_waitcnt vmcnt(2)" ::: "memory");
    else        asm volatile("s_waitcnt vmcnt(0)" ::: "memory");
    SBAR();

    // ---------- q1 ----------
    readFrags(aB + 8192);
    LGKM0(); SBAR();
    stageB((t0 + 2) * 64);
    SBAR();
    if (c < 15) { P2a = *(const float4*)(aSrc + cb + 16);
                  P2b = *(const float4*)(aSrc + cb + 20); }
    SBAR();
    mfma32();
    SBAR();
    if (c < 15) asm volatile("s_waitcnt vmcnt(2)" ::: "memory");
    else        asm volatile("s_waitcnt vmcnt(0)" ::: "memory");
    SBAR();

    // ---------- q2 ----------
    readFrags(aB + 2 * 8192);
    LGKM0(); SBAR();
    stageB((t0 + 3) * 64);
    SBAR();
    if (c < 15) { P3a = *(const float4*)(aSrc + cb + 24);
                  P3b = *(const float4*)(aSrc + cb + 28); }
    SBAR();
    mfma32();
    SBAR();
    if (c < 15) asm volatile("s_waitcnt vmcnt(2)" ::: "memory");
    else        asm volatile("s_waitcnt vmcnt(0)" ::: "memory");
    SBAR();

    // ---------- q3 (+ chunk c+1 LDS write) ----------
    readFrags(aB + 3 * 8192);
    LGKM0(); SBAR();
    if (c < 15) stageB((t0 + 4) * 64);
    SBAR();
    if (c < 14) { N0a = *(const float4*)(aSrc + (c + 2) * 256);
                  N0b = *(const float4*)(aSrc + (c + 2) * 256 + 4); }
    SBAR();
    if (c < 15) {
      // safe: all waves passed chunk-c-1's post-bar => done reading this buffer
      char* wB = (char*)&ldsA[(c + 1) & 1][0];
      wrA(wB, 0, P0a, P0b); wrA(wB, 1, P1a, P1b);   // implicit vmcnt waits P regs
      wrA(wB, 2, P2a, P2b); wrA(wB, 3, P3a, P3b);
    }
    SBAR();
    mfma32();
    SBAR();
    if (c < 14)      asm volatile("s_waitcnt vmcnt(2)" ::: "memory");
    else if (c < 15) asm volatile("s_waitcnt vmcnt(0)" ::: "memory");
    LGKM0();
    if (c < 15) FULL_BAR();     // chunk c+1 visible to all waves
    P0a = N0a; P0b = N0b;
  }

  // epilogue: C/D layout col=lane&15, row=(lane>>4)*4+r; fused bias + fp16 store
  #pragma unroll
  for (int m = 0; m < 4; ++m) {
    #pragma unroll
    for (int n = 0; n < 4; ++n) {
      int col = wc + n * 16 + l15;
      float bv = bias[col];
      #pragma unroll
      for (int r = 0; r < 4; ++r) {
        int row = rowBase + m * 16 + q4 * 4 + r;
        Q[(size_t)row * KDIM + col] = (_Float16)(acc[m][n][r] + bv);
      }
    }
  }
}

// ---------------- GEMM2 pipelined (unchanged from R9/R10) ----------------
__global__ __launch_bounds__(512, 2)
void gemm2_pipe(const _Float16* __restrict__ Aq, const _Float16* __restrict__ Bk,
                float* __restrict__ outp) {
  __shared__ __align__(16) _Float16 ldsA[2][256 * 64];
  __shared__ __align__(16) _Float16 ldsB[2][256 * 64];

  const int tid  = threadIdx.x;
  const int lane = tid & 63;
  const int wid  = tid >> 6;
  const int cpx  = gridDim.x >> 3;
  const int bid  = (blockIdx.x & 7) * cpx + (blockIdx.x >> 3);
  const int nCol = NKEYS / 256;
  const int rowBase = (bid / nCol) * 256;
  const int colBase = (bid % nCol) * 256;
  const int wm = wid >> 2;
  const int wn = wid & 3;
  const int l15 = lane & 15;
  const int q4  = lane >> 4;
  const int sub   = lane >> 3;
  const int gslot = (lane & 7) ^ sub;

  const _Float16* aSrc = Aq + (size_t)rowBase * KDIM;
  const _Float16* bSrc = Bk + (size_t)colBase * KDIM;

  auto stageHalf = [&](const _Float16* src, char* ldsbase, int kt, int h) {
    #pragma unroll
    for (int j = 0; j < 2; ++j) {
      int g = h * 16 + wid * 2 + j;
      gload_lds16(src + (size_t)(g * 8 + sub) * KDIM + kt + gslot * 8,
                  ldsbase + g * 1024);
    }
  };
  auto ld8 = [&](const char* base, int row, int s) {
    return *(const half8*)(base + row * 128 + ((s * 16) ^ ((row & 7) << 4)));
  };

  floatx4 acc[8][4];
  #pragma unroll
  for (int m = 0; m < 8; ++m)
    #pragma unroll
    for (int n = 0; n < 4; ++n)
      acc[m][n] = (floatx4)0.0f;

  stageHalf(aSrc, (char*)ldsA[0], 0, 0);
  stageHalf(aSrc, (char*)ldsA[0], 0, 1);
  stageHalf(bSrc, (char*)ldsB[0], 0, 0);
  stageHalf(bSrc, (char*)ldsB[0], 0, 1);
  stageHalf(aSrc, (char*)ldsA[1], 64, 0);
  stageHalf(aSrc, (char*)ldsA[1], 64, 1);
  stageHalf(bSrc, (char*)ldsB[1], 64, 0);
  stageHalf(bSrc, (char*)ldsB[1], 64, 1);
  asm volatile("s_waitcnt vmcnt(8)" ::: "memory");
  FULL_BAR();

  for (int t = 0; t < 8; ++t) {
    const char* bA = (const char*)ldsA[t & 1];
    const char* bB = (const char*)ldsB[t & 1];
    char* sA = (char*)ldsA[t & 1];
    char* sB = (char*)ldsB[t & 1];
    const int ktn = (t + 2) * 64;
    const bool st = (t < 6);

    half8 a[4][2], b[4][2];

    #pragma unroll
    for (int m = 0; m < 4; ++m)
      #pragma unroll
      for (int kk = 0; kk < 2; ++kk)
        a[m][kk] = ld8(bA, wm * 128 + m * 16 + l15, kk * 4 + q4);
    #pragma unroll
    for (int n = 0; n < 4; ++n)
      #pragma unroll
      for (int kk = 0; kk < 2; ++kk)
        b[n][kk] = ld8(bB, wn * 64 + n * 16 + l15, kk * 4 + q4);
    FULL_BAR();
    asm volatile("s_waitcnt lgkmcnt(0)" ::: "memory");
    __builtin_amdgcn_sched_barrier(0);
    __builtin_amdgcn_s_setprio(1);
    #pragma unroll
    for (int m = 0; m < 4; ++m)
      #pragma unroll
      for (int n = 0; n < 2; ++n)
        #pragma unroll
        for (int kk = 0; kk < 2; ++kk)
          acc[m][n] = __builtin_amdgcn_mfma_f32_16x16x32_f16(a[m][kk], b[n][kk], acc[m][n], 0, 0, 0);
    __builtin_amdgcn_s_setprio(0);
    FULL_BAR();

    if (st) stageHalf(bSrc, sB, ktn, 0);
    __builtin_amdgcn_sched_barrier(0);
    __builtin_amdgcn_s_setprio(1);
    #pragma unroll
    for (int m = 0; m < 4; ++m)
      #pragma unroll
      for (int n = 2; n < 4; ++n)
        #pragma unroll
        for (int kk = 0; kk < 2; ++kk)
          acc[m][n] = __builtin_amdgcn_mfma_f32_16x16x32_f16(a[m][kk], b[n][kk], acc[m][n], 0, 0, 0);
    __builtin_amdgcn_s_setprio(0);
    FULL_BAR();

    #pragma unroll
    for (int m = 0; m < 4; ++m)
      #pragma unroll
      for (int kk = 0; kk < 2; ++kk)
        a[m][kk] = ld8(bA, wm * 128 + (m + 4) * 16 + l15, kk * 4 + q4);
    if (st) stageHalf(bSrc, sB, ktn, 1);
    FULL_BAR();
    asm volatile("s_waitcnt lgkmcnt(0)" ::: "memory");
    __builtin_amdgcn_sched_barrier(0);
    __builtin_amdgcn_s_setprio(1);
    #pragma unroll
    for (int m = 0; m < 4; ++m)
      #pragma unroll
      for (int n = 0; n < 2; ++n)
        #pragma unroll
        for (int kk = 0; kk < 2; ++kk)
          acc[m + 4][n] = __builtin_amdgcn_mfma_f32_16x16x32_f16(a[m][kk], b[n][kk], acc[m + 4][n], 0, 0, 0);
    __builtin_amdgcn_s_setprio(0);
    FULL_BAR();

    if (st) { stageHalf(aSrc, sA, ktn, 0); stageHalf(aSrc, sA, ktn, 1); }
    __builtin_amdgcn_sched_barrier(0);
    __builtin_amdgcn_s_setprio(1);
    #pragma unroll
    for (int m = 0; m < 4; ++m)
      #pragma unroll
      for (int n = 2; n < 4; ++n)
        #pragma unroll
        for (int kk = 0; kk < 2; ++kk)
          acc[m + 4][n] = __builtin_amdgcn_mfma_f32_16x16x32_f16(a[m][kk], b[n][kk], acc[m + 4][n], 0, 0, 0);
    __builtin_amdgcn_s_setprio(0);
    __builtin_amdgcn_sched_barrier(0);
    if (t < 6)      asm volatile("s_waitcnt vmcnt(8)" ::: "memory");
    else if (t == 6) asm volatile("s_waitcnt vmcnt(0)" ::: "memory");
    FULL_BAR();
  }

  #pragma unroll
  for (int m = 0; m < 8; ++m) {
    #pragma unroll
    for (int n = 0; n < 4; ++n) {
      int col = colBase + wn * 64 + n * 16 + l15;
      #pragma unroll
      for (int r = 0; r < 4; ++r) {
        int row = rowBase + wm * 128 + m * 16 + q4 * 4 + r;
        outp[(size_t)row * NKEYS + col] = acc[m][n][r];
      }
    }
  }
}

// ---------------- top-16 + scatter-softmax gates (radix-select) ----------------
__global__ __launch_bounds__(256) void topk_gates_kernel(const float* __restrict__ scores,
                                                         float* __restrict__ gates) {
  __shared__ uint32_t hist[4096];
  __shared__ uint32_t sA[256];
  __shared__ uint32_t av[16], ai[16];
  __shared__ uint32_t sk[KTOP], si[KTOP];
  __shared__ uint32_t cntA, cntC;
  __shared__ int s_p; __shared__ uint32_t s_above;
  __shared__ float gk[KTOP]; __shared__ float s_gother;

  const int tid  = threadIdx.x;
  const int lane = tid & 63;
  const int w    = tid >> 6;
  const float* srow = scores + (size_t)blockIdx.x * NKEYS;

  uint4 z4 = {0, 0, 0, 0};
  #pragma unroll
  for (int i = 0; i < 4; ++i) ((uint4*)hist)[tid + 256 * i] = z4;
  if (tid == 0) { cntA = 0; cntC = 0; }

  uint32_t key[16];
  const int base = (w << 10) + (lane << 4);
  {
    const float4* p4 = (const float4*)(srow + base);
    #pragma unroll
    for (int i = 0; i < 4; ++i) {
      float4 t = p4[i];
      float tv[4] = { t.x, t.y, t.z, t.w };
      #pragma unroll
      for (int c = 0; c < 4; ++c) {
        uint32_t u = __float_as_uint(tv[c]);
        key[i * 4 + c] = u ^ (uint32_t)(((int32_t)u >> 31) | 0x80000000);
      }
    }
  }
  __syncthreads();

  #pragma unroll
  for (int j = 0; j < 16; ++j) atomicAdd(&hist[key[j] >> 20], 1u);
  __syncthreads();

  uint32_t h[16];
  #pragma unroll
  for (int i = 0; i < 16; ++i) h[i] = hist[tid * 16 + i];
  uint32_t sfx[17]; sfx[16] = 0;
  #pragma unroll
  for (int i = 15; i >= 0; --i) sfx[i] = sfx[i + 1] + h[i];
  sA[tid] = sfx[0];
  __syncthreads();
  uint32_t s = sfx[0];
  #pragma unroll
  for (int off = 1; off < 256; off <<= 1) {
    uint32_t add = (tid + off < 256) ? sA[tid + off] : 0;
    __syncthreads();
    s += add; sA[tid] = s;
    __syncthreads();
  }
  const uint32_t exclHi = s - sfx[0];

  #pragma unroll
  for (int i = 0; i < 16; ++i) {
    uint32_t cg = exclHi + sfx[i + 1];
    if (cg < KTOP && cg + h[i] >= KTOP) { s_p = tid * 16 + i; s_above = cg; }
  }
  __syncthreads();
  const uint32_t p = (uint32_t)s_p;
  const uint32_t above = s_above;
  const uint32_t need = KTOP - above;

  uint32_t* ck = hist;
  uint32_t* ci = hist + 2048;
  #pragma unroll
  for (int j = 0; j < 16; ++j) {
    uint32_t b = key[j] >> 20;
    if (b >= p) {
      uint32_t idx = (uint32_t)(base + j);
      if (b > p) { uint32_t pos = atomicAdd(&cntA, 1u); av[pos] = key[j]; ai[pos] = idx; }
      else       { uint32_t pos = atomicAdd(&cntC, 1u); if (pos < 2048u) { ck[pos] = key[j]; ci[pos] = idx; } }
    }
  }
  __syncthreads();

  const uint32_t nA = cntA;
  if (tid < nA) { sk[tid] = av[tid]; si[tid] = ai[tid]; }

  if (w == 0) {
    const uint32_t nC = min(cntC, 2048u);
    for (uint32_t k = 0; k < need; ++k) {
      uint32_t bk = 0, bi = 0xFFFFFFFFu, bp = 0;
      for (uint32_t c = lane; c < nC; c += 64) {
        uint32_t kk = ck[c], ii = ci[c];
        if (kk > bk || (kk == bk && ii < bi)) { bk = kk; bi = ii; bp = c; }
      }
      #pragma unroll
      for (int off = 32; off >= 1; off >>= 1) {
        uint32_t ok = __shfl_down(bk, off);
        uint32_t oi = __shfl_down(bi, off);
        uint32_t op = __shfl_down(bp, off);
        if (ok > bk || (ok == bk && oi < bi)) { bk = ok; bi = oi; bp = op; }
      }
      bp = __shfl(bp, 0);
      if (lane == 0) { ck[bp] = 0; sk[nA + k] = bk; si[nA + k] = bi; }
    }
  }
  __syncthreads();

  if (tid == 0) {
    float f[KTOP]; float mx = 0.f;
    #pragma unroll
    for (int k = 0; k < KTOP; ++k) {
      uint32_t kk = sk[k];
      float fv = (kk & 0x80000000u) ? __uint_as_float(kk ^ 0x80000000u)
                                    : __uint_as_float(~kk);
      f[k] = fv; mx = fmaxf(mx, fv);
    }
    float eo = __expf(-mx);
    float Z = (float)(NKEYS - KTOP) * eo;
    float e[KTOP];
    #pragma unroll
    for (int k = 0; k < KTOP; ++k) { e[k] = __expf(f[k] - mx); Z += e[k]; }
    float inv = 1.f / Z;
    #pragma unroll
    for (int k = 0; k < KTOP; ++k) gk[k] = e[k] * inv;
    s_gother = eo * inv;
  }
  __syncthreads();

  float go = s_gother;
  float4 g4 = { go, go, go, go };
  float* grow = gates + (size_t)blockIdx.x * NKEYS;
  #pragma unroll
  for (int j = 0; j < 4; ++j) ((float4*)grow)[j * 256 + tid] = g4;
  __syncthreads();
  if (tid < KTOP) grow[si[tid]] = gk[tid];
}

extern "C" void kernel_launch(void* const* d_in, const int* in_sizes, int n_in,
                              void* d_out, int out_size, void* d_ws, size_t ws_size,
                              hipStream_t stream) {
  const float* x    = (const float*)d_in[0];
  const float* keys = (const float*)d_in[1];
  const float* W    = (const float*)d_in[2];
  const float* bias = (const float*)d_in[3];
  (void)in_sizes; (void)n_in; (void)out_size; (void)ws_size;

  float* gates  = (float*)d_out;
  float* scores = (float*)d_out + (size_t)BS_T * NKEYS;

  _Float16* W_h = (_Float16*)d_ws;                 // 4 MB
  _Float16* k_h = W_h + (size_t)KDIM * XDIM;       // 4 MB
  _Float16* q_h = k_h + (size_t)NKEYS * KDIM;      // 16 MB

  cvt_f32_f16_v<<<dim3(1024), dim3(256), 0, stream>>>(W, W_h, KDIM * XDIM / 8);
  cvt_f32_f16_v<<<dim3(1024), dim3(256), 0, stream>>>(keys, k_h, NKEYS * KDIM / 8);

  // query = x @ W^T + b -> q_h (fp16). x read ONCE, 1KB-row-chunk staging, grid 256
  gemm1_pipe<<<dim3(BS_T / 64), dim3(512), 0, stream>>>(x, W_h, bias, q_h);

  // scores = q @ keys^T -> fp32. 256x256 tiles, counted-vmcnt pipeline, grid 1024
  gemm2_pipe<<<dim3((BS_T / 256) * (NKEYS / 256)), dim3(512), 0, stream>>>(
      q_h, k_h, scores);

  topk_gates_kernel<<<dim3(BS_T), dim3(256), 0, stream>>>(scores, gates);
}

// Round 14
// 347.661 us; speedup vs baseline: 1.0623x; 1.0623x over previous
//
#include <hip/hip_runtime.h>
#include <stdint.h>

#define BS_T   16384
#define XDIM   4096
#define KDIM   512
#define NKEYS  4096
#define KTOP   16

typedef _Float16 half8  __attribute__((ext_vector_type(8)));
typedef float    floatx4 __attribute__((ext_vector_type(4)));

// async global->LDS, 16B per lane; LDS dest is wave-uniform base + lane*16
__device__ static inline void gload_lds16(const void* g, void* l) {
  __builtin_amdgcn_global_load_lds(
      (const __attribute__((address_space(1))) uint32_t*)(uintptr_t)g,
      (__attribute__((address_space(3))) uint32_t*)(uint32_t)(uintptr_t)l,
      16, 0, 0);
}

#define SBAR() __builtin_amdgcn_sched_barrier(0)
#define LGKM0() asm volatile("s_waitcnt lgkmcnt(0)" ::: "memory")
#define FULL_BAR() do { __builtin_amdgcn_sched_barrier(0); \
                        __builtin_amdgcn_s_barrier(); \
                        __builtin_amdgcn_sched_barrier(0); } while (0)

// ---------------- fp32 -> fp16 convert (vectorized, grid-stride) ----------------
__global__ __launch_bounds__(256) void cvt_f32_f16_v(const float* __restrict__ in,
                                                     _Float16* __restrict__ out, int n8) {
  int stride = gridDim.x * 256;
  for (int i = blockIdx.x * 256 + threadIdx.x; i < n8; i += stride) {
    float4 v0 = ((const float4*)in)[2 * i];
    float4 v1 = ((const float4*)in)[2 * i + 1];
    half8 h = { (_Float16)v0.x, (_Float16)v0.y, (_Float16)v0.z, (_Float16)v0.w,
                (_Float16)v1.x, (_Float16)v1.y, (_Float16)v1.z, (_Float16)v1.w };
    ((half8*)out)[i] = h;
  }
}

// ---------------- GEMM1 v9: Q[M,512] = cvt16(X[M,4096]) @ W16^T + b ---------------
// v6's proven schedule (1 barrier/K-tile, wave-private dbuf B, counted vmcnt) with
// ONE delta: A staged per 128-K chunk -> each x row fetched in 512B contiguous runs
// (per-thread 64B), raising DRAM run length 256B->512B. A = single 16KB buffer
// (both sub-tiles of the chunk), written at even-step start behind the chunk
// boundary barrier (all waves provably past their last read). B unchanged from v6.
// FIFO ledger (VMEM issue order per chunk): [A(c+1)4 after stageB(2c+2)8]:
//   even entering (post-writeA): [B(2c+1)8]; +stage8 +A4 = 20; gate vmcnt(12)
//   odd  entering: [B(2c+2)8, A(c+1)4]; +stage8 = 20; gate vmcnt(12)
//   writeA implicit wait = vmcnt(8) (A oldest). Prologue vmcnt(8); tail c=31: 0.
__global__ __launch_bounds__(512, 1)
void gemm1_pipe(const float* __restrict__ X, const _Float16* __restrict__ Wh,
                const float* __restrict__ bias, _Float16* __restrict__ Q) {
  __shared__ __align__(16) _Float16 ldsA[64 * 128];      // 16 KB (one 128-K chunk)
  __shared__ __align__(16) _Float16 ldsB[2][512 * 64];   // 2 x 64 KB

  const int tid  = threadIdx.x;
  const int lane = tid & 63;
  const int wid  = tid >> 6;            // 0..7
  const int rowBase = blockIdx.x * 64;
  const int wc  = wid * 64;
  const int l15 = lane & 15;
  const int q4  = lane >> 4;
  const int sub   = lane >> 3;
  const int gslot = (lane & 7) ^ sub;

  // A chunk staging: thread -> row tid>>3, 64B span s=tid&7 (floats s*16..s*16+15)
  // per row: 8 threads x 64B = 512B contiguous per chunk fetch
  const int arow = tid >> 3;
  const int s    = tid & 7;
  const float* aSrc = X + (size_t)(rowBase + arow) * XDIM + s * 16;
  const int au    = (s >> 2) * 8192;    // sub-tile (64-k) within chunk
  const int abyte = arow * 128;
  const int aswz  = (arow & 7) << 4;
  const int w0    = (s & 3) * 2;        // two 16B slots w0, w0+1

  // B staging: wave w stages its own rows wc..wc+63 (wave-private)
  const _Float16* const bSrc = Wh + (size_t)(wc + sub) * XDIM + gslot * 8;

  auto stageB = [&](int kt, int buf) {
    char* bd = (char*)&ldsB[buf][0] + wid * 8192;
    #pragma unroll
    for (int i = 0; i < 8; ++i)
      gload_lds16(bSrc + (size_t)i * 8 * XDIM + kt, bd + i * 1024);
  };
  auto writeA = [&](float4 v0, float4 v1, float4 v2, float4 v3) {
    half8 h0 = { (_Float16)v0.x, (_Float16)v0.y, (_Float16)v0.z, (_Float16)v0.w,
                 (_Float16)v1.x, (_Float16)v1.y, (_Float16)v1.z, (_Float16)v1.w };
    half8 h1 = { (_Float16)v2.x, (_Float16)v2.y, (_Float16)v2.z, (_Float16)v2.w,
                 (_Float16)v3.x, (_Float16)v3.y, (_Float16)v3.z, (_Float16)v3.w };
    *(half8*)((char*)ldsA + au + abyte + ((w0 * 16) ^ aswz)) = h0;
    *(half8*)((char*)ldsA + au + abyte + (((w0 + 1) * 16) ^ aswz)) = h1;
  };
  auto ld8 = [&](const char* base, int row, int sl) {
    return *(const half8*)(base + row * 128 + ((sl * 16) ^ ((row & 7) << 4)));
  };

  floatx4 acc[4][4];
  #pragma unroll
  for (int m = 0; m < 4; ++m)
    #pragma unroll
    for (int n = 0; n < 4; ++n)
      acc[m][n] = (floatx4)0.0f;

  half8 a[4][2], b[4][2];
  auto readFrags = [&](const char* aB, const char* bB) {
    #pragma unroll
    for (int m = 0; m < 4; ++m)
      #pragma unroll
      for (int kk = 0; kk < 2; ++kk)
        a[m][kk] = ld8(aB, m * 16 + l15, kk * 4 + q4);
    #pragma unroll
    for (int n = 0; n < 4; ++n)
      #pragma unroll
      for (int kk = 0; kk < 2; ++kk)
        b[n][kk] = ld8(bB, wc + n * 16 + l15, kk * 4 + q4);
  };
  auto mfma32 = [&]() {
    __builtin_amdgcn_s_setprio(1);
    #pragma unroll
    for (int m = 0; m < 4; ++m)
      #pragma unroll
      for (int n = 0; n < 4; ++n)
        #pragma unroll
        for (int kk = 0; kk < 2; ++kk)
          acc[m][n] = __builtin_amdgcn_mfma_f32_16x16x32_f16(a[m][kk], b[n][kk], acc[m][n], 0, 0, 0);
    __builtin_amdgcn_s_setprio(0);
  };

  // ---- prologue: chunk0 -> ldsA; B(0),B(1) staged ----
  {
    float4 C0 = *(const float4*)(aSrc + 0), C1 = *(const float4*)(aSrc + 4);
    float4 C2 = *(const float4*)(aSrc + 8), C3 = *(const float4*)(aSrc + 12);
    SBAR();
    stageB(0, 0);
    SBAR();
    stageB(64, 1);
    SBAR();
    writeA(C0, C1, C2, C3);           // implicit wait drains chunk0 loads
    LGKM0();
    asm volatile("s_waitcnt vmcnt(8)" ::: "memory");   // retire B(0); B(1) flies
    FULL_BAR();
  }

  float4 N0, N1, N2, N3;              // chunk c+1 regs (loaded even step)

  for (int c = 0; c < 32; ++c) {
    // ---------- step even t=2c ----------
    if (c > 0) {
      writeA(N0, N1, N2, N3);         // chunk c -> ldsA (implicit vmcnt(8))
      LGKM0();
      FULL_BAR();                     // chunk visible before reads
    }
    readFrags((const char*)ldsA, (const char*)&ldsB[0][0]);
    LGKM0(); SBAR();
    if (c < 31) stageB((2 * c + 2) * 64, 0);
    SBAR();
    if (c < 31) {
      const float* nsrc = aSrc + (c + 1) * 128;
      N0 = *(const float4*)(nsrc + 0); N1 = *(const float4*)(nsrc + 4);
      N2 = *(const float4*)(nsrc + 8); N3 = *(const float4*)(nsrc + 12);
    }
    SBAR();
    mfma32();
    SBAR();
    if (c < 31) asm volatile("s_waitcnt vmcnt(12)" ::: "memory");  // B(2c+1) done
    else        asm volatile("s_waitcnt vmcnt(0)"  ::: "memory");  // B(63) done
    FULL_BAR();

    // ---------- step odd t=2c+1 ----------
    readFrags((const char*)ldsA + 8192, (const char*)&ldsB[1][0]);
    LGKM0(); SBAR();
    if (c < 31) stageB((2 * c + 3) * 64, 1);
    SBAR();
    mfma32();
    SBAR();
    if (c < 31) {
      asm volatile("s_waitcnt vmcnt(12)" ::: "memory");            // B(2c+2) done
      FULL_BAR();
    }
  }

  // epilogue: C/D layout col=lane&15, row=(lane>>4)*4+r; fused bias + fp16 store
  #pragma unroll
  for (int m = 0; m < 4; ++m) {
    #pragma unroll
    for (int n = 0; n < 4; ++n) {
      int col = wc + n * 16 + l15;
      float bv = bias[col];
      #pragma unroll
      for (int r = 0; r < 4; ++r) {
        int row = rowBase + m * 16 + q4 * 4 + r;
        Q[(size_t)row * KDIM + col] = (_Float16)(acc[m][n][r] + bv);
      }
    }
  }
}

// ---------------- GEMM2 pipelined (unchanged from R9-R11) ----------------
__global__ __launch_bounds__(512, 2)
void gemm2_pipe(const _Float16* __restrict__ Aq, const _Float16* __restrict__ Bk,
                float* __restrict__ outp) {
  __shared__ __align__(16) _Float16 ldsA[2][256 * 64];
  __shared__ __align__(16) _Float16 ldsB[2][256 * 64];

  const int tid  = threadIdx.x;
  const int lane = tid & 63;
  const int wid  = tid >> 6;
  const int cpx  = gridDim.x >> 3;
  const int bid  = (blockIdx.x & 7) * cpx + (blockIdx.x >> 3);
  const int nCol = NKEYS / 256;
  const int rowBase = (bid / nCol) * 256;
  const int colBase = (bid % nCol) * 256;
  const int wm = wid >> 2;
  const int wn = wid & 3;
  const int l15 = lane & 15;
  const int q4  = lane >> 4;
  const int sub   = lane >> 3;
  const int gslot = (lane & 7) ^ sub;

  const _Float16* aSrc = Aq + (size_t)rowBase * KDIM;
  const _Float16* bSrc = Bk + (size_t)colBase * KDIM;

  auto stageHalf = [&](const _Float16* src, char* ldsbase, int kt, int h) {
    #pragma unroll
    for (int j = 0; j < 2; ++j) {
      int g = h * 16 + wid * 2 + j;
      gload_lds16(src + (size_t)(g * 8 + sub) * KDIM + kt + gslot * 8,
                  ldsbase + g * 1024);
    }
  };
  auto ld8 = [&](const char* base, int row, int s) {
    return *(const half8*)(base + row * 128 + ((s * 16) ^ ((row & 7) << 4)));
  };

  floatx4 acc[8][4];
  #pragma unroll
  for (int m = 0; m < 8; ++m)
    #pragma unroll
    for (int n = 0; n < 4; ++n)
      acc[m][n] = (floatx4)0.0f;

  stageHalf(aSrc, (char*)ldsA[0], 0, 0);
  stageHalf(aSrc, (char*)ldsA[0], 0, 1);
  stageHalf(bSrc, (char*)ldsB[0], 0, 0);
  stageHalf(bSrc, (char*)ldsB[0], 0, 1);
  stageHalf(aSrc, (char*)ldsA[1], 64, 0);
  stageHalf(aSrc, (char*)ldsA[1], 64, 1);
  stageHalf(bSrc, (char*)ldsB[1], 64, 0);
  stageHalf(bSrc, (char*)ldsB[1], 64, 1);
  asm volatile("s_waitcnt vmcnt(8)" ::: "memory");
  FULL_BAR();

  for (int t = 0; t < 8; ++t) {
    const char* bA = (const char*)ldsA[t & 1];
    const char* bB = (const char*)ldsB[t & 1];
    char* sA = (char*)ldsA[t & 1];
    char* sB = (char*)ldsB[t & 1];
    const int ktn = (t + 2) * 64;
    const bool st = (t < 6);

    half8 a[4][2], b[4][2];

    #pragma unroll
    for (int m = 0; m < 4; ++m)
      #pragma unroll
      for (int kk = 0; kk < 2; ++kk)
        a[m][kk] = ld8(bA, wm * 128 + m * 16 + l15, kk * 4 + q4);
    #pragma unroll
    for (int n = 0; n < 4; ++n)
      #pragma unroll
      for (int kk = 0; kk < 2; ++kk)
        b[n][kk] = ld8(bB, wn * 64 + n * 16 + l15, kk * 4 + q4);
    FULL_BAR();
    asm volatile("s_waitcnt lgkmcnt(0)" ::: "memory");
    __builtin_amdgcn_sched_barrier(0);
    __builtin_amdgcn_s_setprio(1);
    #pragma unroll
    for (int m = 0; m < 4; ++m)
      #pragma unroll
      for (int n = 0; n < 2; ++n)
        #pragma unroll
        for (int kk = 0; kk < 2; ++kk)
          acc[m][n] = __builtin_amdgcn_mfma_f32_16x16x32_f16(a[m][kk], b[n][kk], acc[m][n], 0, 0, 0);
    __builtin_amdgcn_s_setprio(0);
    FULL_BAR();

    if (st) stageHalf(bSrc, sB, ktn, 0);
    __builtin_amdgcn_sched_barrier(0);
    __builtin_amdgcn_s_setprio(1);
    #pragma unroll
    for (int m = 0; m < 4; ++m)
      #pragma unroll
      for (int n = 2; n < 4; ++n)
        #pragma unroll
        for (int kk = 0; kk < 2; ++kk)
          acc[m][n] = __builtin_amdgcn_mfma_f32_16x16x32_f16(a[m][kk], b[n][kk], acc[m][n], 0, 0, 0);
    __builtin_amdgcn_s_setprio(0);
    FULL_BAR();

    #pragma unroll
    for (int m = 0; m < 4; ++m)
      #pragma unroll
      for (int kk = 0; kk < 2; ++kk)
        a[m][kk] = ld8(bA, wm * 128 + (m + 4) * 16 + l15, kk * 4 + q4);
    if (st) stageHalf(bSrc, sB, ktn, 1);
    FULL_BAR();
    asm volatile("s_waitcnt lgkmcnt(0)" ::: "memory");
    __builtin_amdgcn_sched_barrier(0);
    __builtin_amdgcn_s_setprio(1);
    #pragma unroll
    for (int m = 0; m < 4; ++m)
      #pragma unroll
      for (int n = 0; n < 2; ++n)
        #pragma unroll
        for (int kk = 0; kk < 2; ++kk)
          acc[m + 4][n] = __builtin_amdgcn_mfma_f32_16x16x32_f16(a[m][kk], b[n][kk], acc[m + 4][n], 0, 0, 0);
    __builtin_amdgcn_s_setprio(0);
    FULL_BAR();

    if (st) { stageHalf(aSrc, sA, ktn, 0); stageHalf(aSrc, sA, ktn, 1); }
    __builtin_amdgcn_sched_barrier(0);
    __builtin_amdgcn_s_setprio(1);
    #pragma unroll
    for (int m = 0; m < 4; ++m)
      #pragma unroll
      for (int n = 2; n < 4; ++n)
        #pragma unroll
        for (int kk = 0; kk < 2; ++kk)
          acc[m + 4][n] = __builtin_amdgcn_mfma_f32_16x16x32_f16(a[m][kk], b[n][kk], acc[m + 4][n], 0, 0, 0);
    __builtin_amdgcn_s_setprio(0);
    __builtin_amdgcn_sched_barrier(0);
    if (t < 6)      asm volatile("s_waitcnt vmcnt(8)" ::: "memory");
    else if (t == 6) asm volatile("s_waitcnt vmcnt(0)" ::: "memory");
    FULL_BAR();
  }

  #pragma unroll
  for (int m = 0; m < 8; ++m) {
    #pragma unroll
    for (int n = 0; n < 4; ++n) {
      int col = colBase + wn * 64 + n * 16 + l15;
      #pragma unroll
      for (int r = 0; r < 4; ++r) {
        int row = rowBase + wm * 128 + m * 16 + q4 * 4 + r;
        outp[(size_t)row * NKEYS + col] = acc[m][n][r];
      }
    }
  }
}

// ---------------- top-16 + scatter-softmax gates (radix-select) ----------------
__global__ __launch_bounds__(256) void topk_gates_kernel(const float* __restrict__ scores,
                                                         float* __restrict__ gates) {
  __shared__ uint32_t hist[4096];
  __shared__ uint32_t sA[256];
  __shared__ uint32_t av[16], ai[16];
  __shared__ uint32_t sk[KTOP], si[KTOP];
  __shared__ uint32_t cntA, cntC;
  __shared__ int s_p; __shared__ uint32_t s_above;
  __shared__ float gk[KTOP]; __shared__ float s_gother;

  const int tid  = threadIdx.x;
  const int lane = tid & 63;
  const int w    = tid >> 6;
  const float* srow = scores + (size_t)blockIdx.x * NKEYS;

  uint4 z4 = {0, 0, 0, 0};
  #pragma unroll
  for (int i = 0; i < 4; ++i) ((uint4*)hist)[tid + 256 * i] = z4;
  if (tid == 0) { cntA = 0; cntC = 0; }

  uint32_t key[16];
  const int base = (w << 10) + (lane << 4);
  {
    const float4* p4 = (const float4*)(srow + base);
    #pragma unroll
    for (int i = 0; i < 4; ++i) {
      float4 t = p4[i];
      float tv[4] = { t.x, t.y, t.z, t.w };
      #pragma unroll
      for (int c = 0; c < 4; ++c) {
        uint32_t u = __float_as_uint(tv[c]);
        key[i * 4 + c] = u ^ (uint32_t)(((int32_t)u >> 31) | 0x80000000);
      }
    }
  }
  __syncthreads();

  #pragma unroll
  for (int j = 0; j < 16; ++j) atomicAdd(&hist[key[j] >> 20], 1u);
  __syncthreads();

  uint32_t h[16];
  #pragma unroll
  for (int i = 0; i < 16; ++i) h[i] = hist[tid * 16 + i];
  uint32_t sfx[17]; sfx[16] = 0;
  #pragma unroll
  for (int i = 15; i >= 0; --i) sfx[i] = sfx[i + 1] + h[i];
  sA[tid] = sfx[0];
  __syncthreads();
  uint32_t s = sfx[0];
  #pragma unroll
  for (int off = 1; off < 256; off <<= 1) {
    uint32_t add = (tid + off < 256) ? sA[tid + off] : 0;
    __syncthreads();
    s += add; sA[tid] = s;
    __syncthreads();
  }
  const uint32_t exclHi = s - sfx[0];

  #pragma unroll
  for (int i = 0; i < 16; ++i) {
    uint32_t cg = exclHi + sfx[i + 1];
    if (cg < KTOP && cg + h[i] >= KTOP) { s_p = tid * 16 + i; s_above = cg; }
  }
  __syncthreads();
  const uint32_t p = (uint32_t)s_p;
  const uint32_t above = s_above;
  const uint32_t need = KTOP - above;

  uint32_t* ck = hist;
  uint32_t* ci = hist + 2048;
  #pragma unroll
  for (int j = 0; j < 16; ++j) {
    uint32_t b = key[j] >> 20;
    if (b >= p) {
      uint32_t idx = (uint32_t)(base + j);
      if (b > p) { uint32_t pos = atomicAdd(&cntA, 1u); av[pos] = key[j]; ai[pos] = idx; }
      else       { uint32_t pos = atomicAdd(&cntC, 1u); if (pos < 2048u) { ck[pos] = key[j]; ci[pos] = idx; } }
    }
  }
  __syncthreads();

  const uint32_t nA = cntA;
  if (tid < nA) { sk[tid] = av[tid]; si[tid] = ai[tid]; }

  if (w == 0) {
    const uint32_t nC = min(cntC, 2048u);
    for (uint32_t k = 0; k < need; ++k) {
      uint32_t bk = 0, bi = 0xFFFFFFFFu, bp = 0;
      for (uint32_t c = lane; c < nC; c += 64) {
        uint32_t kk = ck[c], ii = ci[c];
        if (kk > bk || (kk == bk && ii < bi)) { bk = kk; bi = ii; bp = c; }
      }
      #pragma unroll
      for (int off = 32; off >= 1; off >>= 1) {
        uint32_t ok = __shfl_down(bk, off);
        uint32_t oi = __shfl_down(bi, off);
        uint32_t op = __shfl_down(bp, off);
        if (ok > bk || (ok == bk && oi < bi)) { bk = ok; bi = oi; bp = op; }
      }
      bp = __shfl(bp, 0);
      if (lane == 0) { ck[bp] = 0; sk[nA + k] = bk; si[nA + k] = bi; }
    }
  }
  __syncthreads();

  if (tid == 0) {
    float f[KTOP]; float mx = 0.f;
    #pragma unroll
    for (int k = 0; k < KTOP; ++k) {
      uint32_t kk = sk[k];
      float fv = (kk & 0x80000000u) ? __uint_as_float(kk ^ 0x80000000u)
                                    : __uint_as_float(~kk);
      f[k] = fv; mx = fmaxf(mx, fv);
    }
    float eo = __expf(-mx);
    float Z = (float)(NKEYS - KTOP) * eo;
    float e[KTOP];
    #pragma unroll
    for (int k = 0; k < KTOP; ++k) { e[k] = __expf(f[k] - mx); Z += e[k]; }
    float inv = 1.f / Z;
    #pragma unroll
    for (int k = 0; k < KTOP; ++k) gk[k] = e[k] * inv;
    s_gother = eo * inv;
  }
  __syncthreads();

  float go = s_gother;
  float4 g4 = { go, go, go, go };
  float* grow = gates + (size_t)blockIdx.x * NKEYS;
  #pragma unroll
  for (int j = 0; j < 4; ++j) ((float4*)grow)[j * 256 + tid] = g4;
  __syncthreads();
  if (tid < KTOP) grow[si[tid]] = gk[tid];
}

extern "C" void kernel_launch(void* const* d_in, const int* in_sizes, int n_in,
                              void* d_out, int out_size, void* d_ws, size_t ws_size,
                              hipStream_t stream) {
  const float* x    = (const float*)d_in[0];
  const float* keys = (const float*)d_in[1];
  const float* W    = (const float*)d_in[2];
  const float* bias = (const float*)d_in[3];
  (void)in_sizes; (void)n_in; (void)out_size; (void)ws_size;

  float* gates  = (float*)d_out;
  float* scores = (float*)d_out + (size_t)BS_T * NKEYS;

  _Float16* W_h = (_Float16*)d_ws;                 // 4 MB
  _Float16* k_h = W_h + (size_t)KDIM * XDIM;       // 4 MB
  _Float16* q_h = k_h + (size_t)NKEYS * KDIM;      // 16 MB

  cvt_f32_f16_v<<<dim3(1024), dim3(256), 0, stream>>>(W, W_h, KDIM * XDIM / 8);
  cvt_f32_f16_v<<<dim3(1024), dim3(256), 0, stream>>>(keys, k_h, NKEYS * KDIM / 8);

  // query = x @ W^T + b -> q_h (fp16). x read ONCE, 512B-run chunked-A, grid 256
  gemm1_pipe<<<dim3(BS_T / 64), dim3(512), 0, stream>>>(x, W_h, bias, q_h);

  // scores = q @ keys^T -> fp32. 256x256 tiles, counted-vmcnt pipeline, grid 1024
  gemm2_pipe<<<dim3((BS_T / 256) * (NKEYS / 256)), dim3(512), 0, stream>>>(
      q_h, k_h, scores);

  topk_gates_kernel<<<dim3(BS_T), dim3(256), 0, stream>>>(scores, gates);
}